// Round 11
// baseline (184.828 us; speedup 1.0000x reference)
//
#include <hip/hip_runtime.h>
#include <hip/hip_bf16.h>
#include <cstdint>

#define NBATCH 512
#define NDIM   2048
#define NHEADS 16
#define NCPH   128

typedef __bf16 bf16x8 __attribute__((ext_vector_type(8)));
typedef __bf16 bf16x4 __attribute__((ext_vector_type(4)));
typedef float  f32x4  __attribute__((ext_vector_type(4)));

__device__ __forceinline__ unsigned short f2bf(float f) {
    uint32_t u = __builtin_bit_cast(uint32_t, f);
    u += 0x7FFFu + ((u >> 16) & 1u);   // round-to-nearest-even
    return (unsigned short)(u >> 16);
}

__device__ __forceinline__ void gl_lds16(const void* g, void* l) {
    __builtin_amdgcn_global_load_lds(
        (const __attribute__((address_space(1))) void*)g,
        (__attribute__((address_space(3))) void*)l,
        16, 0, 0);
}

// ---------------- x: f32 -> bf16 (2 MiB result, L2-resident for gemm1) --
__global__ __launch_bounds__(256) void cvt_x(
    const float* __restrict__ x, unsigned short* __restrict__ ox)
{
    const int t = blockIdx.x * 256 + threadIdx.x;
    float4 v = ((const float4*)x)[t];
    ushort4 o;
    o.x = f2bf(v.x); o.y = f2bf(v.y); o.z = f2bf(v.z); o.w = f2bf(v.w);
    ((ushort4*)ox)[t] = o;
}

// ---------------- tall-tile bf16 GEMM: C[m,n] = sum_k A[m,k]B[n,k] -----
// BM=128 (tall: A panel = whole M -> A, 2MB bf16, stays hot in EVERY
// XCD's L2), BN narrow, grid (N/BN, 4) so XCD = nblock%8: each B n-panel
// is consumed by its 4 m-blocks on ONE XCD -> B streams exactly once.
// (r6/r8/r10 lesson: 64x64 tiles moved ~512MB through L2/L3 = 40us;
// this shape moves ~50MB.)  A: bf16 gl_lds w/ pre-swizzled src (rule
// #21); B: f32 reg-staged -> cvt -> swizzled ds_write.  4 waves split M.
// BNP: v-half blocks (n0>=NDIM) emit per-tile BN sums.
template<int BN, int BK, bool BNP>
__global__ __launch_bounds__(256) void gemm_tall(
    const unsigned short* __restrict__ Abf, const float* __restrict__ Bf,
    float* __restrict__ C, const float* __restrict__ bias,
    float* __restrict__ bnpart, int M, int N, int K)
{
    constexpr int BM = 128;
    constexpr int MI = 2;                 // wave = 32 rows
    constexpr int NI = BN / 16;
    constexpr int GA = (BM * BK) / 2048;  // gl_lds rounds for A
    constexpr int BPT4 = (BN * BK) / 1024;// B float4 loads per thread (1|2)
    constexpr int CPRB = BK / 8;          // 8-elem chunks per B row

    __shared__ unsigned short As[2][BM * BK];
    __shared__ unsigned short Bs[2][BN * BK];

    const int tid  = threadIdx.x;
    const int lane = tid & 63;
    const int wid  = tid >> 6;
    const int m0   = blockIdx.y * BM;
    const int n0   = blockIdx.x * BN;    // fast dim -> XCD = nblock%8
    const int fr   = lane & 15;
    const int kq   = lane >> 4;

    f32x4 acc[MI][NI] = {};
    float4 rb[BPT4];

    // B staging coords
    const int brow = (BPT4 == 2) ? tid / CPRB : tid >> 4;
    const int bch  = (BPT4 == 2) ? tid % CPRB : ((tid & 15) >> 1);
    const int bhalf = (BPT4 == 2) ? 0 : (tid & 1);

    auto loadA = [&](int bs, int k0) {
#pragma unroll
        for (int r = 0; r < GA; r++) {
            const int e    = r * 2048 + tid * 8;
            const int row  = e / BK;
            const int chk  = (e % BK) >> 3;
            gl_lds16(Abf + (size_t)(m0 + row) * K + k0
                         + ((chk ^ (row & 7)) << 3), &As[bs][e]);
        }
    };
    auto loadB = [&](int k0) {
        if constexpr (BPT4 == 2) {
            const float4* g = (const float4*)(Bf + (size_t)(n0 + brow) * K
                                              + k0 + bch * 8);
            rb[0] = g[0];
            rb[1] = g[1];
        } else {
            rb[0] = *(const float4*)(Bf + (size_t)(n0 + brow) * K + k0
                                     + bch * 8 + bhalf * 4);
        }
    };
    auto writeB = [&](int bs) {
        const int base = brow * BK + ((bch ^ (brow & 7)) << 3);
        if constexpr (BPT4 == 2) {
            bf16x8 v;
            v[0] = (__bf16)rb[0].x; v[1] = (__bf16)rb[0].y;
            v[2] = (__bf16)rb[0].z; v[3] = (__bf16)rb[0].w;
            v[4] = (__bf16)rb[1].x; v[5] = (__bf16)rb[1].y;
            v[6] = (__bf16)rb[1].z; v[7] = (__bf16)rb[1].w;
            *(bf16x8*)&Bs[bs][base] = v;
        } else {
            bf16x4 v;
            v[0] = (__bf16)rb[0].x; v[1] = (__bf16)rb[0].y;
            v[2] = (__bf16)rb[0].z; v[3] = (__bf16)rb[0].w;
            *(bf16x4*)&Bs[bs][base + bhalf * 4] = v;
        }
    };
    auto compute = [&](int bs) {
#pragma unroll
        for (int kh = 0; kh < BK / 32; kh++) {
            const int kchunk = kh * 4 + kq;
            bf16x8 af[MI], bfv[NI];
#pragma unroll
            for (int i = 0; i < MI; i++) {
                const int row = wid * 32 + i * 16 + fr;
                af[i] = *(const bf16x8*)&As[bs][row * BK
                        + ((kchunk ^ (row & 7)) << 3)];
            }
#pragma unroll
            for (int j = 0; j < NI; j++) {
                const int row = j * 16 + fr;
                bfv[j] = *(const bf16x8*)&Bs[bs][row * BK
                         + ((kchunk ^ (row & 7)) << 3)];
            }
#pragma unroll
            for (int i = 0; i < MI; i++)
#pragma unroll
                for (int j = 0; j < NI; j++)
                    acc[i][j] = __builtin_amdgcn_mfma_f32_16x16x32_bf16(
                        af[i], bfv[j], acc[i][j], 0, 0, 0);
        }
    };

    loadA(0, 0);
    loadB(0);
    writeB(0);
    __syncthreads();

    const int NT = K / BK;
    int cur = 0;
    for (int t = 0; t < NT - 1; t++) {
        loadB((t + 1) * BK);           // issue early (cold stream)
        loadA(cur ^ 1, (t + 1) * BK);  // async gl_lds into other buffer
        compute(cur);                  // MFMA covers load latency
        writeB(cur ^ 1);
        __syncthreads();
        cur ^= 1;
    }
    compute(cur);

    const int row0 = m0 + wid * 32 + (kq << 2);
    const int col0 = n0 + fr;
#pragma unroll
    for (int j = 0; j < NI; j++) {
        const int cc = col0 + j * 16;
        const float badd = bias ? bias[cc] : 0.0f;
#pragma unroll
        for (int i = 0; i < MI; i++)
#pragma unroll
            for (int r = 0; r < 4; r++)
                C[(size_t)(row0 + i * 16 + r) * N + cc] = acc[i][j][r] + badd;
    }

    if (BNP && n0 >= NDIM) {
        float s = 0.f, ss = 0.f;
#pragma unroll
        for (int i = 0; i < MI; i++)
#pragma unroll
            for (int j = 0; j < NI; j++)
#pragma unroll
                for (int r = 0; r < 4; r++) {
                    const float v = acc[i][j][r];
                    s += v;
                    ss = fmaf(v, v, ss);
                }
#pragma unroll
        for (int off = 32; off; off >>= 1) {
            s  += __shfl_down(s, off);
            ss += __shfl_down(ss, off);
        }
        __shared__ float rs[4], rss[4];
        if (lane == 0) { rs[wid] = s; rss[wid] = ss; }
        __syncthreads();
        if (tid == 0)   // idx = nvblk*4 + mblk : 64*4 = 256 partials
            ((float2*)bnpart)[((n0 - NDIM) >> 5) * 4 + (m0 >> 7)] =
                make_float2(rs[0] + rs[1] + rs[2] + rs[3],
                            rss[0] + rss[1] + rss[2] + rss[3]);
    }
}

// ---------------- fused BN-final + outer-product + softmax + PV --------
// Single-pass no-max softmax (|logit| <~ 30 << 88: exp can't overflow;
// shift-invariance => same result). All 16 bias float4 in flight upfront.
// Lanes 0-15 reduce this head's 16 BN partials -> (scale, shift).
// one block per (b,h); thread pair (2c,2c+1) owns row c, 64 elems each.
__global__ __launch_bounds__(256) void attn_k(
    const float* __restrict__ qv, const float* __restrict__ kparam,
    const float* __restrict__ bias, const float* __restrict__ temperature,
    const float* __restrict__ bnpart, const float* __restrict__ gamma,
    const float* __restrict__ beta, unsigned short* __restrict__ aout)
{
    const int bh = blockIdx.x;
    const int b  = bh >> 4;
    const int h  = bh & 15;
    const int tid = threadIdx.x;

    __shared__ float ks[NCPH], vsr[NCPH], s2sh[2];
    if (tid < 32)
        ((float4*)ks)[tid] =
            ((const float4*)(kparam + (size_t)b * NDIM + h * NCPH))[tid];
    else if (tid < 64)
        ((float4*)vsr)[tid - 32] =
            ((const float4*)(qv + (size_t)b * (2 * NDIM) + NDIM + h * NCPH))[tid - 32];

    if (tid < 16) {   // BN finalize: 16 partials for this head
        float2 p = ((const float2*)bnpart)[h * 16 + tid];
        float s = p.x, ss = p.y;
#pragma unroll
        for (int off = 8; off; off >>= 1) {
            s  += __shfl_xor(s, off);
            ss += __shfl_xor(ss, off);
        }
        if (tid == 0) {
            const float inv = 1.0f / (NBATCH * NCPH);
            float mean = s * inv;
            float var  = ss * inv - mean * mean;
            float sc   = gamma[h] * rsqrtf(var + 1e-5f);
            s2sh[0] = sc;
            s2sh[1] = beta[h] - mean * sc;
        }
    }

    const int c = tid >> 1, half = tid & 1;
    const float qc   = qv[(size_t)b * (2 * NDIM) + h * NCPH + c];
    const float temp = temperature[h];

    // all 64 bias values in flight before any dependent compute
    const float4* bp = (const float4*)(bias + ((size_t)bh << 14)
                                       + (size_t)c * NCPH + half * 64);
    float4 l4[16];
#pragma unroll
    for (int j = 0; j < 16; j++) l4[j] = bp[j];

    __syncthreads();
    const float sc = s2sh[0], sh = s2sh[1];
    const float4* kk4 = (const float4*)(ks  + half * 64);
    const float4* vv4 = (const float4*)(vsr + half * 64);

    float s0 = 0.f, s1 = 0.f, o0 = 0.f, o1 = 0.f;
#pragma unroll
    for (int j = 0; j < 16; j++) {
        const float4 bb = l4[j];
        const float4 kx = kk4[j];
        const float4 vx = vv4[j];
        float px = __expf(fmaf(qc, kx.x, bb.x) * temp);
        float py = __expf(fmaf(qc, kx.y, bb.y) * temp);
        float pz = __expf(fmaf(qc, kx.z, bb.z) * temp);
        float pw = __expf(fmaf(qc, kx.w, bb.w) * temp);
        s0 += px; s1 += py; s0 += pz; s1 += pw;
        o0 = fmaf(px, vx.x, o0);
        o1 = fmaf(py, vx.y, o1);
        o0 = fmaf(pz, vx.z, o0);
        o1 = fmaf(pw, vx.w, o1);
    }
    float s = s0 + s1, o = o0 + o1;
    s += __shfl_xor(s, 1);
    o += __shfl_xor(o, 1);

    if (half == 0)
        aout[(size_t)b * NDIM + h * NCPH + c] = f2bf(fmaf(sc, o / s, sh));
}

// ------------------------------ launch ---------------------------------
extern "C" void kernel_launch(void* const* d_in, const int* in_sizes, int n_in,
                              void* d_out, int out_size, void* d_ws, size_t ws_size,
                              hipStream_t stream)
{
    const float* x      = (const float*)d_in[0];
    const float* Wqv    = (const float*)d_in[1];
    const float* temp   = (const float*)d_in[2];
    const float* kparam = (const float*)d_in[3];
    const float* bias   = (const float*)d_in[4];
    const float* gamma  = (const float*)d_in[5];
    const float* beta   = (const float*)d_in[6];
    const float* Wout   = (const float*)d_in[7];
    const float* bout   = (const float*)d_in[8];
    float* out = (float*)d_out;

    char* ws = (char*)d_ws;
    float*          qv     = (float*)(ws);                      // 8 MiB
    unsigned short* ao_bf  = (unsigned short*)(ws + 8388608);   // 2 MiB
    float*          bnpart = (float*)(ws + 10485760);           // 2 KiB
    unsigned short* x_bf   = (unsigned short*)(ws + 10487808);  // 2 MiB

    cvt_x<<<1024, 256, 0, stream>>>(x, x_bf);

    // qv = x @ W_qv^T : M=512, N=4096, K=2048
    // grid (128 n-blocks, 4 m-blocks): XCD = nb%8; B streams once/XCD
    gemm_tall<32, 64, true><<<dim3(128, 4), 256, 0, stream>>>(
        x_bf, Wqv, qv, nullptr, bnpart, NBATCH, 2 * NDIM, NDIM);

    attn_k<<<NBATCH * NHEADS, 256, 0, stream>>>(
        qv, kparam, bias, temp, bnpart, gamma, beta, ao_bf);

    // out = attn_out @ W_out^T + b_out : M=512, N=2048, K=2048
    gemm_tall<16, 64, false><<<dim3(128, 4), 256, 0, stream>>>(
        ao_bf, Wout, out, bout, nullptr, NBATCH, NDIM, NDIM);
}

// Round 12
// 170.898 us; speedup vs baseline: 1.0815x; 1.0815x over previous
//
#include <hip/hip_runtime.h>
#include <hip/hip_bf16.h>
#include <cstdint>

#define NBATCH 512
#define NDIM   2048
#define NHEADS 16
#define NCPH   128

typedef __bf16 bf16x8 __attribute__((ext_vector_type(8)));
typedef float  f32x4  __attribute__((ext_vector_type(4)));

__device__ __forceinline__ unsigned short f2bf(float f) {
    uint32_t u = __builtin_bit_cast(uint32_t, f);
    u += 0x7FFFu + ((u >> 16) & 1u);   // round-to-nearest-even
    return (unsigned short)(u >> 16);
}

// ---------------- x: f32 -> bf16 (2 MiB result, L2-resident for gemm1) --
__global__ __launch_bounds__(256) void cvt_x(
    const float* __restrict__ x, unsigned short* __restrict__ ox)
{
    const int t = blockIdx.x * 256 + threadIdx.x;
    float4 v = ((const float4*)x)[t];
    ushort4 o;
    o.x = f2bf(v.x); o.y = f2bf(v.y); o.z = f2bf(v.z); o.w = f2bf(v.w);
    ((ushort4*)ox)[t] = o;
}

// ---------------- B-resident barrier-free GEMM -------------------------
// C[m,n] = sum_k A[m,k]*B[n,k] (+bias[n]);  K = 2048, BN = 32.
// Phase 1 (once): block's whole B n-panel (32 x 2048 f32) -> cvt -> LDS
// as bf16 (128 KB exactly), XOR-swizzled (chunk ^= row&15 -> ds_read_b128
// hits each bank uniformly = conflict-free).  One barrier.
// Phase 2: K-loop with NO barriers: A bf16 fragments load global->reg
// 4 K-steps ahead (named sets a0..a3, static idx per rule #20); A (2 MB)
// is L2-hot on every XCD.  Compiler emits counted vmcnt/lgkm waits from
// register deps -- the per-step vmcnt(0) barrier drain that capped every
// r6-r11 staged variant (MfmaUtil 8%, r8 counters) does not exist here.
// 8 waves x 512 thr; grid = N/32 x (512/BM) = 256 blocks = 1/CU; the
// M-split blocks of one n-panel share an XCD (id%8 = nb%8) -> B streams
// HBM exactly once.  BNP: v-half blocks emit BN sums (Bs reused as red).
template<int BM, bool BNP>
__global__ __launch_bounds__(512) void gemm_bres(
    const unsigned short* __restrict__ Abf, const float* __restrict__ Bf,
    float* __restrict__ C, const float* __restrict__ bias,
    float* __restrict__ bnpart, int N)
{
    constexpr int MI = BM / 128;            // rows/wave/16: 2 (g1) | 1 (g2)
    __shared__ unsigned short Bs[32 * 2048];   // 128 KiB

    const int tid  = threadIdx.x;           // 0..511
    const int lane = tid & 63;
    const int wv   = tid >> 6;              // 0..7
    const int m0   = blockIdx.y * BM;
    const int n0   = blockIdx.x * 32;
    const int fr   = lane & 15;
    const int kq   = lane >> 4;
    const int mw   = m0 + wv * (MI * 16);

    // ---- phase 1: B panel -> LDS (bf16, swizzled) ----
    {
        const int r  = tid >> 4;            // 0..31 panel row
        const int c0 = tid & 15;
#pragma unroll
        for (int it = 0; it < 16; it++) {
            const int kc = c0 + it * 16;    // 8-elem chunk index 0..255
            const float4* g = (const float4*)(Bf + (size_t)(n0 + r) * 2048
                                              + kc * 8);
            float4 v0 = g[0], v1 = g[1];
            bf16x8 v;
            v[0] = (__bf16)v0.x; v[1] = (__bf16)v0.y;
            v[2] = (__bf16)v0.z; v[3] = (__bf16)v0.w;
            v[4] = (__bf16)v1.x; v[5] = (__bf16)v1.y;
            v[6] = (__bf16)v1.z; v[7] = (__bf16)v1.w;
            *(bf16x8*)&Bs[r * 2048 + ((kc ^ (r & 15)) << 3)] = v;
        }
    }
    __syncthreads();

    // ---- phase 2: barrier-free K-loop ----
    f32x4 acc[MI][2] = {};
    bf16x8 a0[MI], a1[MI], a2[MI], a3[MI];

    auto ldA = [&](bf16x8 (&d)[MI], int t) {
#pragma unroll
        for (int i = 0; i < MI; i++)
            d[i] = *(const bf16x8*)(Abf + (size_t)(mw + i * 16 + fr) * 2048
                                    + t * 32 + kq * 8);
    };
    auto step = [&](bf16x8 (&a)[MI], int t) {
#pragma unroll
        for (int j = 0; j < 2; j++) {
            const int row = j * 16 + fr;
            bf16x8 b = *(const bf16x8*)&Bs[row * 2048
                        + (((4 * t + kq) ^ (row & 15)) << 3)];
#pragma unroll
            for (int i = 0; i < MI; i++)
                acc[i][j] = __builtin_amdgcn_mfma_f32_16x16x32_bf16(
                    a[i], b, acc[i][j], 0, 0, 0);
        }
    };

    ldA(a0, 0); ldA(a1, 1); ldA(a2, 2); ldA(a3, 3);
    for (int t = 0; t < 64; t += 4) {
        step(a0, t);     if (t + 4 < 64) ldA(a0, t + 4);
        step(a1, t + 1); if (t + 5 < 64) ldA(a1, t + 5);
        step(a2, t + 2); if (t + 6 < 64) ldA(a2, t + 6);
        step(a3, t + 3); if (t + 7 < 64) ldA(a3, t + 7);
    }

    // ---- epilogue ----
    const int row0 = mw + (kq << 2);
    const int col0 = n0 + fr;
#pragma unroll
    for (int j = 0; j < 2; j++) {
        const int cc = col0 + j * 16;
        const float badd = bias ? bias[cc] : 0.0f;
#pragma unroll
        for (int i = 0; i < MI; i++)
#pragma unroll
            for (int r = 0; r < 4; r++)
                C[(size_t)(row0 + i * 16 + r) * N + cc] = acc[i][j][r] + badd;
    }

    if (BNP && n0 >= NDIM) {
        float s = 0.f, ss = 0.f;
#pragma unroll
        for (int i = 0; i < MI; i++)
#pragma unroll
            for (int j = 0; j < 2; j++)
#pragma unroll
                for (int r = 0; r < 4; r++) {
                    const float v = acc[i][j][r];
                    s += v;
                    ss = fmaf(v, v, ss);
                }
#pragma unroll
        for (int off = 32; off; off >>= 1) {
            s  += __shfl_down(s, off);
            ss += __shfl_down(ss, off);
        }
        float* red = (float*)Bs;            // B no longer needed
        __syncthreads();
        if (lane == 0) { red[wv] = s; red[8 + wv] = ss; }
        __syncthreads();
        if (tid == 0) {
            float S = 0.f, SS = 0.f;
#pragma unroll
            for (int w = 0; w < 8; w++) { S += red[w]; SS += red[8 + w]; }
            // idx = vnb*2 + mb : 64*2 = 128 partials
            ((float2*)bnpart)[((n0 - NDIM) >> 5) * 2 + (m0 >> 8)] =
                make_float2(S, SS);
        }
    }
}

// ---------------- fused BN-final + outer-product + softmax + PV --------
// Single-pass no-max softmax (|logit| <~ 30 << 88: exp can't overflow;
// shift-invariance => same result). All 16 bias float4 in flight upfront.
// Lanes 0-7 reduce this head's 8 BN partials -> (scale, shift).
// one block per (b,h); thread pair (2c,2c+1) owns row c, 64 elems each.
__global__ __launch_bounds__(256) void attn_k(
    const float* __restrict__ qv, const float* __restrict__ kparam,
    const float* __restrict__ bias, const float* __restrict__ temperature,
    const float* __restrict__ bnpart, const float* __restrict__ gamma,
    const float* __restrict__ beta, unsigned short* __restrict__ aout)
{
    const int bh = blockIdx.x;
    const int b  = bh >> 4;
    const int h  = bh & 15;
    const int tid = threadIdx.x;

    __shared__ float ks[NCPH], vsr[NCPH], s2sh[2];
    if (tid < 32)
        ((float4*)ks)[tid] =
            ((const float4*)(kparam + (size_t)b * NDIM + h * NCPH))[tid];
    else if (tid < 64)
        ((float4*)vsr)[tid - 32] =
            ((const float4*)(qv + (size_t)b * (2 * NDIM) + NDIM + h * NCPH))[tid - 32];

    if (tid < 8) {   // BN finalize: 8 partials for this head
        float2 p = ((const float2*)bnpart)[h * 8 + tid];
        float s = p.x, ss = p.y;
#pragma unroll
        for (int off = 4; off; off >>= 1) {
            s  += __shfl_xor(s, off);
            ss += __shfl_xor(ss, off);
        }
        if (tid == 0) {
            const float inv = 1.0f / (NBATCH * NCPH);
            float mean = s * inv;
            float var  = ss * inv - mean * mean;
            float sc   = gamma[h] * rsqrtf(var + 1e-5f);
            s2sh[0] = sc;
            s2sh[1] = beta[h] - mean * sc;
        }
    }

    const int c = tid >> 1, half = tid & 1;
    const float qc   = qv[(size_t)b * (2 * NDIM) + h * NCPH + c];
    const float temp = temperature[h];

    // all 64 bias values in flight before any dependent compute
    const float4* bp = (const float4*)(bias + ((size_t)bh << 14)
                                       + (size_t)c * NCPH + half * 64);
    float4 l4[16];
#pragma unroll
    for (int j = 0; j < 16; j++) l4[j] = bp[j];

    __syncthreads();
    const float sc = s2sh[0], sh = s2sh[1];
    const float4* kk4 = (const float4*)(ks  + half * 64);
    const float4* vv4 = (const float4*)(vsr + half * 64);

    float s0 = 0.f, s1 = 0.f, o0 = 0.f, o1 = 0.f;
#pragma unroll
    for (int j = 0; j < 16; j++) {
        const float4 bb = l4[j];
        const float4 kx = kk4[j];
        const float4 vx = vv4[j];
        float px = __expf(fmaf(qc, kx.x, bb.x) * temp);
        float py = __expf(fmaf(qc, kx.y, bb.y) * temp);
        float pz = __expf(fmaf(qc, kx.z, bb.z) * temp);
        float pw = __expf(fmaf(qc, kx.w, bb.w) * temp);
        s0 += px; s1 += py; s0 += pz; s1 += pw;
        o0 = fmaf(px, vx.x, o0);
        o1 = fmaf(py, vx.y, o1);
        o0 = fmaf(pz, vx.z, o0);
        o1 = fmaf(pw, vx.w, o1);
    }
    float s = s0 + s1, o = o0 + o1;
    s += __shfl_xor(s, 1);
    o += __shfl_xor(o, 1);

    if (half == 0)
        aout[(size_t)b * NDIM + h * NCPH + c] = f2bf(fmaf(sc, o / s, sh));
}

// ------------------------------ launch ---------------------------------
extern "C" void kernel_launch(void* const* d_in, const int* in_sizes, int n_in,
                              void* d_out, int out_size, void* d_ws, size_t ws_size,
                              hipStream_t stream)
{
    const float* x      = (const float*)d_in[0];
    const float* Wqv    = (const float*)d_in[1];
    const float* temp   = (const float*)d_in[2];
    const float* kparam = (const float*)d_in[3];
    const float* bias   = (const float*)d_in[4];
    const float* gamma  = (const float*)d_in[5];
    const float* beta   = (const float*)d_in[6];
    const float* Wout   = (const float*)d_in[7];
    const float* bout   = (const float*)d_in[8];
    float* out = (float*)d_out;

    char* ws = (char*)d_ws;
    float*          qv     = (float*)(ws);                      // 8 MiB
    unsigned short* ao_bf  = (unsigned short*)(ws + 8388608);   // 2 MiB
    float*          bnpart = (float*)(ws + 10485760);           // 2 KiB
    unsigned short* x_bf   = (unsigned short*)(ws + 10487808);  // 2 MiB

    cvt_x<<<1024, 256, 0, stream>>>(x, x_bf);

    // qv = x @ W_qv^T : M=512, N=4096, K=2048
    // grid (128 n-panels, 2 m-halves) = 256 blocks = 1/CU
    gemm_bres<256, true><<<dim3(128, 2), 512, 0, stream>>>(
        x_bf, Wqv, qv, nullptr, bnpart, 2 * NDIM);

    attn_k<<<NBATCH * NHEADS, 256, 0, stream>>>(
        qv, kparam, bias, temp, bnpart, gamma, beta, ao_bf);

    // out = attn_out @ W_out^T + b_out : M=512, N=2048, K=2048
    gemm_bres<128, false><<<dim3(64, 4), 512, 0, stream>>>(
        ao_bf, Wout, out, bout, nullptr, NDIM);
}

// Round 13
// 163.101 us; speedup vs baseline: 1.1332x; 1.0478x over previous
//
#include <hip/hip_runtime.h>
#include <hip/hip_bf16.h>
#include <cstdint>

#define NBATCH 512
#define NDIM   2048
#define NHEADS 16
#define NCPH   128

typedef __bf16 bf16x8 __attribute__((ext_vector_type(8)));
typedef float  f32x4  __attribute__((ext_vector_type(4)));

__device__ __forceinline__ unsigned short f2bf(float f) {
    uint32_t u = __builtin_bit_cast(uint32_t, f);
    u += 0x7FFFu + ((u >> 16) & 1u);   // round-to-nearest-even
    return (unsigned short)(u >> 16);
}

__device__ __forceinline__ void gl_lds16(const void* g, void* l) {
    __builtin_amdgcn_global_load_lds(
        (const __attribute__((address_space(1))) void*)g,
        (__attribute__((address_space(3))) void*)l,
        16, 0, 0);
}

// ---------------- bf16-MFMA GEMM with in-kernel f32->bf16 staging -------
// C[m,n] = sum_k A[m,k]*B[n,k] (+bias[n]).  Identical to the r6 kernel
// (best measured) except BK=128: 16 K-steps instead of 32.  r8's counters
// showed each barrier-to-barrier step costs ~3300cy dominated by a FIXED
// latency+drain component (MfmaUtil 8%, VALU 12%, HBM 15%); halving the
// step count attacks that directly.  Occupancy preserved: gemm1 LDS 64KB
// -> still 2 blocks/CU (was already 2); gemm2 48KB -> 3.
// B always f32 reg-staged -> cvt -> swizzled ds_write; A f32 (gemm1) or
// bf16 via global_load_lds w/ pre-swizzled src (gemm2, rule #21).
// BNP: v-half blocks (n0>=NDIM) emit per-tile BN sums (s, ss).
template<int BM, int BN, int BK, bool A_BF16, bool BNP>
__global__ __launch_bounds__(256) void gemm_f(
    const unsigned short* __restrict__ Abf, const float* __restrict__ Af,
    const float* __restrict__ Bf, float* __restrict__ C,
    const float* __restrict__ bias, float* __restrict__ bnpart,
    int M, int N, int K)
{
    constexpr int WM = BM / 2, WN = BN / 2;
    constexpr int MI = WM / 16, NI = WN / 16;
    constexpr int CPR = BK / 8;              // 8-elem chunks per row
    constexpr int RA = (BM * BK) / 8 / 256;  // f32-A chunk rounds
    constexpr int GA = (BM * BK) / 2048;     // bf16-A gl_lds rounds
    constexpr int RB = (BN * BK) / 8 / 256;  // f32-B chunk rounds

    __shared__ unsigned short As[2][BM * BK];
    __shared__ unsigned short Bs[2][BN * BK];

    const int tid  = threadIdx.x;
    const int lane = tid & 63;
    const int wid  = tid >> 6;
    const int wr   = wid >> 1;
    const int wc   = wid & 1;
    const int m0   = blockIdx.y * BM;
    const int n0   = blockIdx.x * BN;   // fast dim: XCD = n-block%8
    const int fr   = lane & 15;
    const int kq   = lane >> 4;

    f32x4 acc[MI][NI] = {};
    float4 rga[RA > 0 ? RA : 1][2], rgb[RB][2];

    auto load_A = [&](int bs, int k0) {
        if constexpr (A_BF16) {
#pragma unroll
            for (int r = 0; r < GA; r++) {
                const int e   = r * 2048 + tid * 8;
                const int row = e / BK;
                const int swz = ((((e % BK) >> 3) ^ (row & 7)) << 3);
                gl_lds16(Abf + (size_t)(m0 + row) * K + k0 + swz, &As[bs][e]);
            }
        } else {
#pragma unroll
            for (int r = 0; r < RA; r++) {
                const int idx = r * 256 + tid;
                const int row = idx / CPR, cc = idx % CPR;
                const float4* g = (const float4*)(Af + (size_t)(m0 + row) * K
                                                  + k0 + cc * 8);
                rga[r][0] = g[0];
                rga[r][1] = g[1];
            }
        }
    };
    auto load_B = [&](int k0) {
#pragma unroll
        for (int r = 0; r < RB; r++) {
            const int idx = r * 256 + tid;
            const int row = idx / CPR, cc = idx % CPR;
            const float4* g = (const float4*)(Bf + (size_t)(n0 + row) * K
                                              + k0 + cc * 8);
            rgb[r][0] = g[0];
            rgb[r][1] = g[1];
        }
    };
    auto write_A = [&](int bs) {
        if constexpr (!A_BF16) {
#pragma unroll
            for (int r = 0; r < RA; r++) {
                const int idx = r * 256 + tid;
                const int row = idx / CPR, cc = idx % CPR;
                bf16x8 v;
                v[0] = (__bf16)rga[r][0].x; v[1] = (__bf16)rga[r][0].y;
                v[2] = (__bf16)rga[r][0].z; v[3] = (__bf16)rga[r][0].w;
                v[4] = (__bf16)rga[r][1].x; v[5] = (__bf16)rga[r][1].y;
                v[6] = (__bf16)rga[r][1].z; v[7] = (__bf16)rga[r][1].w;
                *(bf16x8*)&As[bs][row * BK + ((cc ^ (row & 7)) << 3)] = v;
            }
        }
    };
    auto write_B = [&](int bs) {
#pragma unroll
        for (int r = 0; r < RB; r++) {
            const int idx = r * 256 + tid;
            const int row = idx / CPR, cc = idx % CPR;
            bf16x8 v;
            v[0] = (__bf16)rgb[r][0].x; v[1] = (__bf16)rgb[r][0].y;
            v[2] = (__bf16)rgb[r][0].z; v[3] = (__bf16)rgb[r][0].w;
            v[4] = (__bf16)rgb[r][1].x; v[5] = (__bf16)rgb[r][1].y;
            v[6] = (__bf16)rgb[r][1].z; v[7] = (__bf16)rgb[r][1].w;
            *(bf16x8*)&Bs[bs][row * BK + ((cc ^ (row & 7)) << 3)] = v;
        }
    };
    auto compute = [&](int bs) {
#pragma unroll
        for (int kh = 0; kh < BK / 32; kh++) {
            const int kchunk = kh * 4 + kq;
            bf16x8 af[MI], bfv[NI];
#pragma unroll
            for (int i = 0; i < MI; i++) {
                const int row = wr * WM + i * 16 + fr;
                af[i] = *(const bf16x8*)&As[bs][row * BK
                        + ((kchunk ^ (row & 7)) << 3)];
            }
#pragma unroll
            for (int j = 0; j < NI; j++) {
                const int row = wc * WN + j * 16 + fr;
                bfv[j] = *(const bf16x8*)&Bs[bs][row * BK
                         + ((kchunk ^ (row & 7)) << 3)];
            }
#pragma unroll
            for (int i = 0; i < MI; i++)
#pragma unroll
                for (int j = 0; j < NI; j++)
                    acc[i][j] = __builtin_amdgcn_mfma_f32_16x16x32_bf16(
                        af[i], bfv[j], acc[i][j], 0, 0, 0);
        }
    };

    load_A(0, 0);
    load_B(0);
    write_A(0);
    write_B(0);
    __syncthreads();

    const int NT = K / BK;
    int cur = 0;
    for (int t = 0; t < NT - 1; t++) {
        load_A(cur ^ 1, (t + 1) * BK);   // issue early (A_BF16: gl_lds direct)
        load_B((t + 1) * BK);            // issue early
        compute(cur);                    // MFMA hides global latency
        write_A(cur ^ 1);                // waits loads, cvt, ds_write
        write_B(cur ^ 1);
        __syncthreads();
        cur ^= 1;
    }
    compute(cur);

    const int row0 = m0 + wr * WM + (kq << 2);
    const int col0 = n0 + wc * WN + fr;
#pragma unroll
    for (int j = 0; j < NI; j++) {
        const int cc = col0 + j * 16;
        const float badd = bias ? bias[cc] : 0.0f;
#pragma unroll
        for (int i = 0; i < MI; i++)
#pragma unroll
            for (int r = 0; r < 4; r++)
                C[(size_t)(row0 + i * 16 + r) * N + cc] = acc[i][j][r] + badd;
    }

    if (BNP && n0 >= NDIM) {
        float s = 0.f, ss = 0.f;
#pragma unroll
        for (int i = 0; i < MI; i++)
#pragma unroll
            for (int j = 0; j < NI; j++)
#pragma unroll
                for (int r = 0; r < 4; r++) {
                    const float v = acc[i][j][r];
                    s += v;
                    ss = fmaf(v, v, ss);
                }
#pragma unroll
        for (int off = 32; off; off >>= 1) {
            s  += __shfl_down(s, off);
            ss += __shfl_down(ss, off);
        }
        __shared__ float rs[4], rss[4];
        if (lane == 0) { rs[wid] = s; rss[wid] = ss; }
        __syncthreads();
        if (tid == 0)
            ((float2*)bnpart)[((n0 - NDIM) >> 6) * 8 + (m0 >> 6)] =
                make_float2(rs[0] + rs[1] + rs[2] + rs[3],
                            rss[0] + rss[1] + rss[2] + rss[3]);
    }
}

// ---------------- fused BN-final + outer-product + softmax + PV --------
// Single-pass no-max softmax (|logit| <~ 30 << 88: exp can't overflow;
// shift-invariance => same result). All 16 bias float4 in flight upfront.
// Lanes 0-15 reduce this head's 16 BN partials -> (scale, shift).
// one block per (b,h); thread pair (2c,2c+1) owns row c, 64 elems each.
__global__ __launch_bounds__(256) void attn_k(
    const float* __restrict__ qv, const float* __restrict__ kparam,
    const float* __restrict__ bias, const float* __restrict__ temperature,
    const float* __restrict__ bnpart, const float* __restrict__ gamma,
    const float* __restrict__ beta, unsigned short* __restrict__ aout)
{
    const int bh = blockIdx.x;
    const int b  = bh >> 4;
    const int h  = bh & 15;
    const int tid = threadIdx.x;

    __shared__ float ks[NCPH], vsr[NCPH], s2sh[2];
    if (tid < 32)
        ((float4*)ks)[tid] =
            ((const float4*)(kparam + (size_t)b * NDIM + h * NCPH))[tid];
    else if (tid < 64)
        ((float4*)vsr)[tid - 32] =
            ((const float4*)(qv + (size_t)b * (2 * NDIM) + NDIM + h * NCPH))[tid - 32];

    if (tid < 16) {   // BN finalize: 16 partials for this head
        float2 p = ((const float2*)bnpart)[(h * 2 + (tid >> 3)) * 8 + (tid & 7)];
        float s = p.x, ss = p.y;
#pragma unroll
        for (int off = 8; off; off >>= 1) {
            s  += __shfl_xor(s, off);
            ss += __shfl_xor(ss, off);
        }
        if (tid == 0) {
            const float inv = 1.0f / (NBATCH * NCPH);
            float mean = s * inv;
            float var  = ss * inv - mean * mean;
            float sc   = gamma[h] * rsqrtf(var + 1e-5f);
            s2sh[0] = sc;
            s2sh[1] = beta[h] - mean * sc;
        }
    }

    const int c = tid >> 1, half = tid & 1;
    const float qc   = qv[(size_t)b * (2 * NDIM) + h * NCPH + c];
    const float temp = temperature[h];

    // all 64 bias values in flight before any dependent compute
    const float4* bp = (const float4*)(bias + ((size_t)bh << 14)
                                       + (size_t)c * NCPH + half * 64);
    float4 l4[16];
#pragma unroll
    for (int j = 0; j < 16; j++) l4[j] = bp[j];

    __syncthreads();
    const float sc = s2sh[0], sh = s2sh[1];
    const float4* kk4 = (const float4*)(ks  + half * 64);
    const float4* vv4 = (const float4*)(vsr + half * 64);

    float s0 = 0.f, s1 = 0.f, o0 = 0.f, o1 = 0.f;
#pragma unroll
    for (int j = 0; j < 16; j++) {
        const float4 bb = l4[j];
        const float4 kx = kk4[j];
        const float4 vx = vv4[j];
        float px = __expf(fmaf(qc, kx.x, bb.x) * temp);
        float py = __expf(fmaf(qc, kx.y, bb.y) * temp);
        float pz = __expf(fmaf(qc, kx.z, bb.z) * temp);
        float pw = __expf(fmaf(qc, kx.w, bb.w) * temp);
        s0 += px; s1 += py; s0 += pz; s1 += pw;
        o0 = fmaf(px, vx.x, o0);
        o1 = fmaf(py, vx.y, o1);
        o0 = fmaf(pz, vx.z, o0);
        o1 = fmaf(pw, vx.w, o1);
    }
    float s = s0 + s1, o = o0 + o1;
    s += __shfl_xor(s, 1);
    o += __shfl_xor(o, 1);

    if (half == 0)
        aout[(size_t)b * NDIM + h * NCPH + c] = f2bf(fmaf(sc, o / s, sh));
}

// ------------------------------ launch ---------------------------------
extern "C" void kernel_launch(void* const* d_in, const int* in_sizes, int n_in,
                              void* d_out, int out_size, void* d_ws, size_t ws_size,
                              hipStream_t stream)
{
    const float* x      = (const float*)d_in[0];
    const float* Wqv    = (const float*)d_in[1];
    const float* temp   = (const float*)d_in[2];
    const float* kparam = (const float*)d_in[3];
    const float* bias   = (const float*)d_in[4];
    const float* gamma  = (const float*)d_in[5];
    const float* beta   = (const float*)d_in[6];
    const float* Wout   = (const float*)d_in[7];
    const float* bout   = (const float*)d_in[8];
    float* out = (float*)d_out;

    char* ws = (char*)d_ws;
    float*          qv     = (float*)(ws);                      // 8 MiB
    unsigned short* ao_bf  = (unsigned short*)(ws + 8388608);   // 2 MiB
    float*          bnpart = (float*)(ws + 10485760);           // 2 KiB

    // qv = x @ W_qv^T : M=512, N=4096, K=2048 (512 blocks, BK=128)
    gemm_f<64, 64, 128, false, true><<<dim3(64, 8), 256, 0, stream>>>(
        nullptr, x, Wqv, qv, nullptr, bnpart, NBATCH, 2 * NDIM, NDIM);

    attn_k<<<NBATCH * NHEADS, 256, 0, stream>>>(
        qv, kparam, bias, temp, bnpart, gamma, beta, ao_bf);

    // out = attn_out @ W_out^T + b_out : M=512, N=2048, K=2048 (BK=128)
    gemm_f<64, 32, 128, true, false><<<dim3(64, 8), 256, 0, stream>>>(
        ao_bf, nullptr, Wout, out, bout, nullptr, NBATCH, NDIM, NDIM);
}